// Round 20
// baseline (232.714 us; speedup 1.0000x reference)
//
#include <hip/hip_runtime.h>

// k-means cluster step: N=400000, D=256, K=50 (fp32 in/out).
// Round 20 = r17/r19 with POLE-BALANCED wave roles + epilogue trim:
//  - phase A on 8 waves (8-15) via the r10-validated 16x16x32 convention:
//    per-wave chain halves (8 shallow MFMAs, acc = 4 VGPR). Full K per wave
//    -> ONE sS score buffer (c2 folded). (A LDS reads 2x, but off the pole.)
//  - phase B unchanged from r17: 1 n-tile/wave on ALL 16 waves (16 bacc).
//  - argmin on waves 0-7 (idle in interval 2), 4 points/wave; PT ring-3
//    [50][40] (argmin-write / zero / B-read in 3 distinct buffers), B's
//    a-frag m-rows clamped to 49 (rows >=50 never written back).
//  - epilogue: counts ride the partials; NO memset dispatch, k_reduce
//    covers all OUT_N=12850 deterministically.
// LDS 75.4KB -> 2 blocks/CU; static VGPR ~52 (safe under the 64 wall).

typedef _Float16 f16x8 __attribute__((ext_vector_type(8)));
typedef _Float16 f16x4 __attribute__((ext_vector_type(4)));
typedef float    f32x4 __attribute__((ext_vector_type(4)));
typedef unsigned int u32x4 __attribute__((ext_vector_type(4)));

constexpr int K = 50, KP = 64, D = 256, KD = K * D;
constexpr int OUT_N = KD + K;       // 12850
constexpr int BLK = 1024, GRID = 512, CH = 32;
constexpr int SSTH = 72;   // f16 score stride: 144B rows
constexpr int PST  = 40;   // P^T f16 stride: 80B = 5x16B
constexpr int PTR  = 50;   // P^T rows (clusters actually used)

__global__ __launch_bounds__(BLK)
void k_fused(const float* __restrict__ x, const float* __restrict__ cc,
             float* __restrict__ partial, float* __restrict__ out,
             int N, int useAtomic) {
    __shared__ _Float16       sC[K * D];        // 25.6 KB, 16B-chunk XOR ^(r&7)
    __shared__ unsigned short sxh[2][CH * D];   // 32 KB f16 ring-2
    __shared__ alignas(16) _Float16 sS[32 * SSTH];    // 4.6 KB full f16 scores
    __shared__ alignas(16) _Float16 sPT[3][PTR * PST]; // 12 KB onehot^T ring-3
    __shared__ float          sc2[KP];
    __shared__ int            scnt[K];

    const int tid = threadIdx.x;
    for (int i = tid; i < K * D; i += BLK) sC[i] = (_Float16)0.f;
    for (int i = tid; i < 3 * PTR * PST; i += BLK) sPT[0][i] = (_Float16)0.f;
    if (tid < K) scnt[tid] = 0;
    __syncthreads();
    for (int i = tid; i < KD; i += BLK) {
        int r = i >> 8, col = i & 255, ch = col >> 3, wd = col & 7;
        sC[r * D + (((ch ^ (r & 7)) << 3) | wd)] = (_Float16)cc[i];
    }
    if (tid < KP) {
        float s = 0.f;
        if (tid < K) for (int q = 0; q < D; ++q) { float v = cc[tid * D + q]; s += v * v; }
        sc2[tid] = s;
    }
    __syncthreads();

    const int lane = tid & 63, ci = lane & 15, g = lane >> 4, w = tid >> 6;
    // phase-A role (waves 8-15, r10 convention): pt = point half, ncl = cl tile
    const int pt   = (w - 8) & 1;
    const int ncl  = ((w - 8) >> 1) & 3;
    const int arow = pt * 16 + ci;
    const int akey = (ci & 7) ^ (((ci >> 3) & 1) << 2);   // == key(arow)
    const int acl  = ncl * 16 + ci;                       // cluster col 0..63
    const int ackey = ci & 7;
    const _Float16* cbp = &sC[(acl < K ? acl : K - 1) * D];
    const float INF = 3.4e38f;
    const float c2v = (acl < K) ? sc2[acl] : INF;
    // phase-B role (all 16 waves): output n-tile w; clamped PT m-rows
    const int bcol = w * 16 + ci, bc3 = bcol >> 3, bce = bcol & 7;
    const int pr0 = ci;                                    // m-tile 0 rows 0-15
    const int pr1 = 16 + ci;                               // 16-31
    const int pr2 = 32 + ci;                               // 32-47
    const int pr3 = (48 + ci < K) ? (48 + ci) : (K - 1);   // 48,49 else clamp

    const int nCh = N / CH;
    const int cpb = nCh / gridDim.x, rem = nCh % gridDim.x;
    const int bid = blockIdx.x;
    const int lo  = bid * cpb + (bid < rem ? bid : rem);
    const int cnt = cpb + (bid < rem ? 1 : 0);

    // staging: wave w owns rows 2w,2w+1; lane = row 2w+(l>>5), cols 8c..8c+7
    const int srow = 2 * w + (lane >> 5);
    const int scol = (lane & 31);
    const int skey = (srow & 7) ^ (((srow >> 3) & 1) << 2);
    f32x4 rA = {0,0,0,0}, rB = {0,0,0,0};
#define ISSUE(t_) { const float* b_ = x + (size_t)(t_) * (CH * D) + srow * D + 8 * scol; \
    rA = *(const f32x4*)(b_); rB = *(const f32x4*)(b_ + 4); }
#define WSLOT(s_) { \
    f16x8 h_ = {(_Float16)rA[0], (_Float16)rA[1], (_Float16)rA[2], (_Float16)rA[3], \
                (_Float16)rB[0], (_Float16)rB[1], (_Float16)rB[2], (_Float16)rB[3]}; \
    *(f16x8*)(&sxh[s_][srow * D + ((scol ^ skey) << 3)]) = h_; }

    f32x4 bacc0 = {0,0,0,0}, bacc1 = {0,0,0,0}, bacc2 = {0,0,0,0}, bacc3 = {0,0,0,0};

    // prologue: slot0 <- chunk lo (reg-dep wait auto-inserted); issue lo+1
    if (cnt > 0) { ISSUE(lo) WSLOT(0) if (cnt > 1) ISSUE(lo + 1) }
    __syncthreads();

    for (int i = 0; i <= cnt; ++i) {
        // -------- interval 1: B(i-1) on ALL waves; A(i) on waves 8-15 --------
        if (i >= 1) {                    // phase B: scatter chunk i-1
            const unsigned short* xbh = &sxh[(i - 1) & 1][0];
            const _Float16* ptb = &sPT[(i - 1) % 3][0];
            unsigned short v0, v1, v2, v3, v4, v5, v6, v7;
#define RDH(j) { const int p_ = 8 * g + (j); const int key_ = (j) ^ ((g & 1) << 2); \
            v##j = xbh[p_ * D + ((bc3 ^ key_) << 3) + bce]; }
            RDH(0) RDH(1) RDH(2) RDH(3) RDH(4) RDH(5) RDH(6) RDH(7)
#undef RDH
            unsigned int w0 = (unsigned int)v0 | ((unsigned int)v1 << 16);
            unsigned int w1 = (unsigned int)v2 | ((unsigned int)v3 << 16);
            unsigned int w2 = (unsigned int)v4 | ((unsigned int)v5 << 16);
            unsigned int w3 = (unsigned int)v6 | ((unsigned int)v7 << 16);
            u32x4 W = {w0, w1, w2, w3};
            f16x8 bfr = __builtin_bit_cast(f16x8, W);
            __builtin_amdgcn_s_setprio(1);
#define BMT(PR, ACC) { \
            f16x8 a = *(const f16x8*)(ptb + (PR) * PST + 8 * g); \
            ACC = __builtin_amdgcn_mfma_f32_16x16x32_f16(a, bfr, ACC, 0, 0, 0); }
            BMT(pr0, bacc0) BMT(pr1, bacc1) BMT(pr2, bacc2) BMT(pr3, bacc3)
#undef BMT
            __builtin_amdgcn_s_setprio(0);
        }

        if (w >= 8 && i < cnt) {         // phase A: 16x16 MFMA, 8 waves, full K
            const unsigned short* xb = &sxh[i & 1][0];
            f32x4 acc = {0.f, 0.f, 0.f, 0.f};
            __builtin_amdgcn_s_setprio(1);
#define A_KS(ks) { \
            f16x8 a = *(const f16x8*)(&xb[arow * D + ((((ks) * 4 + g) ^ akey) << 3)]); \
            f16x8 b = *(const f16x8*)(cbp + ((((ks) * 4 + g) ^ ackey) << 3)); \
            acc = __builtin_amdgcn_mfma_f32_16x16x32_f16(a, b, acc, 0, 0, 0); }
            A_KS(0) A_KS(1) A_KS(2) A_KS(3) A_KS(4) A_KS(5) A_KS(6) A_KS(7)
#undef A_KS
            __builtin_amdgcn_s_setprio(0);
            // dump full scores: row(point) = pt*16 + 4g + r, col = acl
            sS[(pt * 16 + 4 * g + 0) * SSTH + acl] = (_Float16)(c2v - 2.f * acc[0]);
            sS[(pt * 16 + 4 * g + 1) * SSTH + acl] = (_Float16)(c2v - 2.f * acc[1]);
            sS[(pt * 16 + 4 * g + 2) * SSTH + acl] = (_Float16)(c2v - 2.f * acc[2]);
            sS[(pt * 16 + 4 * g + 3) * SSTH + acl] = (_Float16)(c2v - 2.f * acc[3]);
        }

        __syncthreads();   // scores(i) visible; slot/PT reads of interval 1 retired

        // ---- interval 2: WSLOT(i+1); ISSUE(i+2); waves 0-7: zero PT + argmin ----
        if (i + 1 < cnt) {
            WSLOT((i + 1) & 1)            // waits ISSUE(i+1) via reg dep only
            if (i + 2 < cnt) ISSUE(lo + i + 2)
        }

        if (w < 8) {
            if (i + 1 < cnt) {           // zero PT[(i+1)%3]: 250 b128 writes
                const int z = w * 64 + lane;
                if (z < (PTR * PST) / 8) {
                    f16x8 zz = {(_Float16)0.f,(_Float16)0.f,(_Float16)0.f,(_Float16)0.f,
                                (_Float16)0.f,(_Float16)0.f,(_Float16)0.f,(_Float16)0.f};
                    *(f16x8*)(&sPT[(i + 1) % 3][z * 8]) = zz;
                }
            }
            if (i < cnt) {               // argmin chunk i: 4 points/wave
                const int p_ = w * 4 + (lane >> 4);   // point 0..31
                const int cg = lane & 15;             // cols 4cg..4cg+3
                f16x4 hv = *(const f16x4*)(&sS[p_ * SSTH + 4 * cg]);
                float bm = (float)hv[0]; int bb = 4 * cg;
                { float s_ = (float)hv[1]; if (s_ < bm) { bm = s_; bb = 4 * cg + 1; } }
                { float s_ = (float)hv[2]; if (s_ < bm) { bm = s_; bb = 4 * cg + 2; } }
                { float s_ = (float)hv[3]; if (s_ < bm) { bm = s_; bb = 4 * cg + 3; } }
                { float pm = __shfl_xor(bm, 1, 64); int pb = __shfl_xor(bb, 1, 64);
                  if (pm < bm || (pm == bm && pb < bb)) { bm = pm; bb = pb; } }
                { float pm = __shfl_xor(bm, 2, 64); int pb = __shfl_xor(bb, 2, 64);
                  if (pm < bm || (pm == bm && pb < bb)) { bm = pm; bb = pb; } }
                { float pm = __shfl_xor(bm, 4, 64); int pb = __shfl_xor(bb, 4, 64);
                  if (pm < bm || (pm == bm && pb < bb)) { bm = pm; bb = pb; } }
                { float pm = __shfl_xor(bm, 8, 64); int pb = __shfl_xor(bb, 8, 64);
                  if (pm < bm || (pm == bm && pb < bb)) { bm = pm; bb = pb; } }
                if (cg == 0) {
                    sPT[i % 3][bb * PST + p_] = (_Float16)1.f;
                    atomicAdd(&scnt[bb], 1);
                }
            }
        }
        __syncthreads();   // slot(i+1), PT zero/ones visible for next iter
    }

    // ---- writeback: D row = M*16+4g+r (cluster), col = bcol; counts -> tail ----
    if (useAtomic) {
#define WBK(M, ACC) { \
        { int cl_ = (M)*16 + 4*g + 0; if (cl_ < K) atomicAdd(&out[cl_ * D + bcol], ACC[0]); } \
        { int cl_ = (M)*16 + 4*g + 1; if (cl_ < K) atomicAdd(&out[cl_ * D + bcol], ACC[1]); } \
        { int cl_ = (M)*16 + 4*g + 2; if (cl_ < K) atomicAdd(&out[cl_ * D + bcol], ACC[2]); } \
        { int cl_ = (M)*16 + 4*g + 3; if (cl_ < K) atomicAdd(&out[cl_ * D + bcol], ACC[3]); } }
        WBK(0, bacc0) WBK(1, bacc1) WBK(2, bacc2) WBK(3, bacc3)
#undef WBK
        __syncthreads();
        for (int k = tid; k < K; k += BLK) atomicAdd(&out[KD + k], (float)scnt[k]);
    } else {
        float* pb = partial + (size_t)bid * OUT_N;
#define WBK(M, ACC) { \
        { int cl_ = (M)*16 + 4*g + 0; if (cl_ < K) pb[cl_ * D + bcol] = ACC[0]; } \
        { int cl_ = (M)*16 + 4*g + 1; if (cl_ < K) pb[cl_ * D + bcol] = ACC[1]; } \
        { int cl_ = (M)*16 + 4*g + 2; if (cl_ < K) pb[cl_ * D + bcol] = ACC[2]; } \
        { int cl_ = (M)*16 + 4*g + 3; if (cl_ < K) pb[cl_ * D + bcol] = ACC[3]; } }
        WBK(0, bacc0) WBK(1, bacc1) WBK(2, bacc2) WBK(3, bacc3)
#undef WBK
        __syncthreads();
        for (int k = tid; k < K; k += BLK) pb[KD + k] = (float)scnt[k];
    }
}

// deterministic reduction over all OUT_N elements (sums + counts); no memset
__global__ __launch_bounds__(256)
void k_reduce(const float* __restrict__ partial, float* __restrict__ out, int G) {
    const int j = blockIdx.x * 256 + threadIdx.x;
    if (j >= OUT_N) return;
    float s = 0.f;
    for (int b = 0; b < G; ++b) s += partial[(size_t)b * OUT_N + j];
    out[j] = s;
}

extern "C" void kernel_launch(void* const* d_in, const int* in_sizes, int n_in,
                              void* d_out, int out_size, void* d_ws, size_t ws_size,
                              hipStream_t stream) {
    const float* x = (const float*)d_in[0];
    const float* c = (const float*)d_in[1];
    float* out = (float*)d_out;
    const int N = in_sizes[0] / D;

    float* partial = (float*)d_ws;
    const size_t need = (size_t)GRID * OUT_N * sizeof(float);
    const int useAtomic = (ws_size < need) ? 1 : 0;

    if (useAtomic) {
        hipMemsetAsync(d_out, 0, (size_t)out_size * sizeof(float), stream);
    }
    k_fused<<<GRID, BLK, 0, stream>>>(x, c, partial, out, N, useAtomic);
    if (!useAtomic) {
        k_reduce<<<(OUT_N + 255) / 256, 256, 0, stream>>>(partial, out, GRID);
    }
}

// Round 21
// 134.354 us; speedup vs baseline: 1.7321x; 1.7321x over previous
//
#include <hip/hip_runtime.h>

// k-means cluster step: N=400000, D=256, K=50 (fp32 in/out).
// FINAL (round 21) = round 17/19 verbatim (session best, reproduced twice:
// 133.5 / 134.2 us, absmax 64). Round 20's pole-balance rewrite regressed
// +73% (stacked PT-zero + argmin on the same waves, doubled A-read
// redundancy) — reverted. Both attempts to reshuffle wave roles (r18, r20)
// regressed; r17's layout is the measured local optimum.
// Structure: ring-2 f16 staging; phase A = X*C^T 32x32 MFMA waves 12-15
// (K-halves); phase B = PT^T*X 16x16 MFMA all 16 waves; argmin waves 8-11;
// PT onehot in LDS; de-pinned scheduling + setprio; 2 barriers/chunk;
// 2 blocks/CU (32 waves/CU = hardware max occupancy).
// Ceiling arithmetic: HBM floor 65us (410MB x read); 2-barrier lockstep
// packing ~50% -> ~134us. All levers past this hit the 64-VGPR wall
// (@max occupancy) or the 80KB-LDS wall (@2 blocks/CU).

typedef _Float16 f16x8 __attribute__((ext_vector_type(8)));
typedef float    f32x4 __attribute__((ext_vector_type(4)));
typedef float    f32x16 __attribute__((ext_vector_type(16)));
typedef unsigned int u32x4 __attribute__((ext_vector_type(4)));

constexpr int K = 50, KP = 64, D = 256, KD = K * D;
constexpr int BLK = 1024, GRID = 512, CH = 32;
constexpr int SSTH = 72;   // f16 score stride: 144B rows, 16B-aligned
constexpr int PST  = 40;   // P^T f16 stride: 80B = 5x16B (uniform bank quads)

__global__ __launch_bounds__(BLK)
void k_fused(const float* __restrict__ x, const float* __restrict__ cc,
             float* __restrict__ partial, float* __restrict__ out,
             int N, int useAtomic) {
    __shared__ _Float16       sC[K * D];        // 25.6 KB, 16B-chunk XOR ^(r&7)
    __shared__ unsigned short sxh[2][CH * D];   // 32 KB f16 ring-2
    __shared__ alignas(16) _Float16 sS0[32 * SSTH];  // 4.6 KB f16 scores, half 0 (+c2)
    __shared__ alignas(16) _Float16 sS1[32 * SSTH];  // 4.6 KB f16 scores, half 1
    __shared__ alignas(16) _Float16 sPT[2][64 * PST]; // 10.2 KB onehot^T ping-pong
    __shared__ float          sc2[KP];
    __shared__ int            scnt[K];

    const int tid = threadIdx.x;
    for (int i = tid; i < K * D; i += BLK) sC[i] = (_Float16)0.f;
    for (int i = tid; i < 2 * 64 * PST; i += BLK) sPT[0][i] = (_Float16)0.f;
    if (tid < K) scnt[tid] = 0;
    __syncthreads();
    for (int i = tid; i < KD; i += BLK) {
        int r = i >> 8, col = i & 255, ch = col >> 3, wd = col & 7;
        sC[r * D + (((ch ^ (r & 7)) << 3) | wd)] = (_Float16)cc[i];
    }
    if (tid < KP) {
        float s = 0.f;
        if (tid < K) for (int q = 0; q < D; ++q) { float v = cc[tid * D + q]; s += v * v; }
        sc2[tid] = s;
    }
    __syncthreads();

    const int lane = tid & 63, ci = lane & 15, g = lane >> 4, w = tid >> 6;
    // phase-A role (waves 12-15): kh = K-half, wA = cluster tile (0/1)
    const int kh   = (w >= 14) ? 1 : 0;
    const int wA   = w & 1;
    const int ra   = lane & 31;               // point row
    const int dl   = lane >> 5;               // k-subgroup
    const int rakey = (ra & 7) ^ (((ra >> 3) & 1) << 2);
    const int cl32 = wA * 32 + (lane & 31);   // cluster col (0..63)
    const int clkey = (lane & 31) & 7;
    const _Float16* cbp = &sC[(cl32 < K ? cl32 : K - 1) * D];  // clamped row
    // phase-B role (all 16 waves): output n-tile w
    const int bcol = w * 16 + ci, bc3 = bcol >> 3, bce = bcol & 7;

    const int nCh = N / CH;
    const int cpb = nCh / gridDim.x, rem = nCh % gridDim.x;
    const int bid = blockIdx.x;
    const int lo  = bid * cpb + (bid < rem ? bid : rem);
    const int cnt = cpb + (bid < rem ? 1 : 0);

    const float INF = 3.4e38f;
    const float c2A = (cl32 < K) ? sc2[cl32] : INF;

    // staging: wave w owns rows 2w,2w+1; lane = row 2w+(l>>5), cols 8c..8c+7
    const int srow = 2 * w + (lane >> 5);
    const int scol = (lane & 31);
    const int skey = (srow & 7) ^ (((srow >> 3) & 1) << 2);
    f32x4 rA = {0,0,0,0}, rB = {0,0,0,0};
#define ISSUE(t_) { const float* b_ = x + (size_t)(t_) * (CH * D) + srow * D + 8 * scol; \
    rA = *(const f32x4*)(b_); rB = *(const f32x4*)(b_ + 4); }
#define WSLOT(s_) { \
    f16x8 h_ = {(_Float16)rA[0], (_Float16)rA[1], (_Float16)rA[2], (_Float16)rA[3], \
                (_Float16)rB[0], (_Float16)rB[1], (_Float16)rB[2], (_Float16)rB[3]}; \
    *(f16x8*)(&sxh[s_][srow * D + ((scol ^ skey) << 3)]) = h_; }

    f32x4 bacc0 = {0,0,0,0}, bacc1 = {0,0,0,0}, bacc2 = {0,0,0,0}, bacc3 = {0,0,0,0};

    // prologue: slot0 <- chunk lo (reg-dep wait auto-inserted); issue lo+1
    if (cnt > 0) { ISSUE(lo) WSLOT(0) if (cnt > 1) ISSUE(lo + 1) }
    __syncthreads();

    for (int i = 0; i <= cnt; ++i) {
        // -------- interval 1: B(i-1) first (short chain), then A(i) --------
        if (i >= 1) {                    // phase B: scatter chunk i-1, all waves
            const unsigned short* xbh = &sxh[(i - 1) & 1][0];
            const _Float16* pt = &sPT[(i - 1) & 1][0];
            unsigned short v0, v1, v2, v3, v4, v5, v6, v7;
#define RDH(j) { const int p_ = 8 * g + (j); const int key_ = (j) ^ ((g & 1) << 2); \
            v##j = xbh[p_ * D + ((bc3 ^ key_) << 3) + bce]; }
            RDH(0) RDH(1) RDH(2) RDH(3) RDH(4) RDH(5) RDH(6) RDH(7)
#undef RDH
            unsigned int w0 = (unsigned int)v0 | ((unsigned int)v1 << 16);
            unsigned int w1 = (unsigned int)v2 | ((unsigned int)v3 << 16);
            unsigned int w2 = (unsigned int)v4 | ((unsigned int)v5 << 16);
            unsigned int w3 = (unsigned int)v6 | ((unsigned int)v7 << 16);
            u32x4 W = {w0, w1, w2, w3};
            f16x8 bfr = __builtin_bit_cast(f16x8, W);
            __builtin_amdgcn_s_setprio(1);
#define BMT(M, ACC) { \
            f16x8 a = *(const f16x8*)(pt + ((M) * 16 + ci) * PST + 8 * g); \
            ACC = __builtin_amdgcn_mfma_f32_16x16x32_f16(a, bfr, ACC, 0, 0, 0); }
            BMT(0, bacc0) BMT(1, bacc1) BMT(2, bacc2) BMT(3, bacc3)
#undef BMT
            __builtin_amdgcn_s_setprio(0);
        }

        if (w >= 12 && i < cnt) {        // phase A: 32x32 MFMA, waves 12-15
            const unsigned short* xb = &sxh[i & 1][0];
            f32x16 acc = {0,0,0,0,0,0,0,0,0,0,0,0,0,0,0,0};
            __builtin_amdgcn_s_setprio(1);
#define A_KS(s) { \
            const int c_ = (kh * 8 + (s)) * 2 + dl; \
            f16x8 a = *(const f16x8*)(&xb[ra * D + ((c_ ^ rakey) << 3)]); \
            f16x8 b = *(const f16x8*)(cbp + ((c_ ^ clkey) << 3)); \
            acc = __builtin_amdgcn_mfma_f32_32x32x16_f16(a, b, acc, 0, 0, 0); }
            A_KS(0) A_KS(1) A_KS(2) A_KS(3) A_KS(4) A_KS(5) A_KS(6) A_KS(7)
#undef A_KS
            __builtin_amdgcn_s_setprio(0);
            if (kh == 0) {
#define DUMP(r) { const int row_ = ((r) & 3) + 8 * ((r) >> 2) + 4 * dl; \
                sS0[row_ * SSTH + cl32] = (_Float16)(c2A - 2.f * acc[r]); }
                DUMP(0) DUMP(1) DUMP(2) DUMP(3) DUMP(4) DUMP(5) DUMP(6) DUMP(7)
                DUMP(8) DUMP(9) DUMP(10) DUMP(11) DUMP(12) DUMP(13) DUMP(14) DUMP(15)
#undef DUMP
            } else {
#define DUMP(r) { const int row_ = ((r) & 3) + 8 * ((r) >> 2) + 4 * dl; \
                sS1[row_ * SSTH + cl32] = (_Float16)(-2.f * acc[r]); }
                DUMP(0) DUMP(1) DUMP(2) DUMP(3) DUMP(4) DUMP(5) DUMP(6) DUMP(7)
                DUMP(8) DUMP(9) DUMP(10) DUMP(11) DUMP(12) DUMP(13) DUMP(14) DUMP(15)
#undef DUMP
            }
        }

        __syncthreads();   // scores(i) visible; slot/PT (i-1)&1 reads retired

        // ---- interval 2: WSLOT(i+1); ISSUE(i+2); zero PT(i+1); argmin(i) ----
        if (i + 1 < cnt) {
            WSLOT((i + 1) & 1)            // waits ISSUE(i+1) via reg dep only
            if (i + 2 < cnt) ISSUE(lo + i + 2)
        }

        if (w < 8 && i + 1 < cnt) {      // zero PT((i+1)&1): 320 b128 writes
            const int z = w * 64 + lane;
            if (z < (64 * PST * 2) / 16) {
                f16x8 zz = {(_Float16)0.f,(_Float16)0.f,(_Float16)0.f,(_Float16)0.f,
                            (_Float16)0.f,(_Float16)0.f,(_Float16)0.f,(_Float16)0.f};
                *(f16x8*)(&sPT[(i + 1) & 1][z * 8]) = zz;
            }
        }

        if (w >= 8 && w < 12 && i < cnt) {   // argmin chunk i, waves 8-11
            const int p_ = (w - 8) * 8 + (lane >> 3);   // point 0..31
            const int q  = lane & 7;                     // col octet
            const _Float16* s0p = &sS0[p_ * SSTH + 8 * q];
            const _Float16* s1p = &sS1[p_ * SSTH + 8 * q];
            f16x8 h0 = *(const f16x8*)(s0p);
            f16x8 h1 = *(const f16x8*)(s1p);
            float bm = (float)h0[0] + (float)h1[0]; int bb = 8 * q;
#define CMP(E) { float s_ = (float)h0[E] + (float)h1[E]; int c_ = 8 * q + (E); \
            if (s_ < bm) { bm = s_; bb = c_; } }
            CMP(1) CMP(2) CMP(3) CMP(4) CMP(5) CMP(6) CMP(7)
#undef CMP
            { float pm = __shfl_xor(bm, 1, 64); int pb = __shfl_xor(bb, 1, 64);
              if (pm < bm || (pm == bm && pb < bb)) { bm = pm; bb = pb; } }
            { float pm = __shfl_xor(bm, 2, 64); int pb = __shfl_xor(bb, 2, 64);
              if (pm < bm || (pm == bm && pb < bb)) { bm = pm; bb = pb; } }
            { float pm = __shfl_xor(bm, 4, 64); int pb = __shfl_xor(bb, 4, 64);
              if (pm < bm || (pm == bm && pb < bb)) { bm = pm; bb = pb; } }
            if (q == 0) {
                sPT[i & 1][bb * PST + p_] = (_Float16)1.f;   // one-write
                atomicAdd(&scnt[bb], 1);
            }
        }
        __syncthreads();   // slot(i+1), PT zero/ones visible for next iter
    }

    // ---- writeback: D row = M*16+4g+r (cluster), col = bcol ----
    if (useAtomic) {
#define WBK(M, ACC) { \
        { int cl_ = (M)*16 + 4*g + 0; if (cl_ < K) atomicAdd(&out[cl_ * D + bcol], ACC[0]); } \
        { int cl_ = (M)*16 + 4*g + 1; if (cl_ < K) atomicAdd(&out[cl_ * D + bcol], ACC[1]); } \
        { int cl_ = (M)*16 + 4*g + 2; if (cl_ < K) atomicAdd(&out[cl_ * D + bcol], ACC[2]); } \
        { int cl_ = (M)*16 + 4*g + 3; if (cl_ < K) atomicAdd(&out[cl_ * D + bcol], ACC[3]); } }
        WBK(0, bacc0) WBK(1, bacc1) WBK(2, bacc2) WBK(3, bacc3)
#undef WBK
    } else {
        float* pb = partial + (size_t)bid * KD;
#define WBK(M, ACC) { \
        { int cl_ = (M)*16 + 4*g + 0; if (cl_ < K) pb[cl_ * D + bcol] = ACC[0]; } \
        { int cl_ = (M)*16 + 4*g + 1; if (cl_ < K) pb[cl_ * D + bcol] = ACC[1]; } \
        { int cl_ = (M)*16 + 4*g + 2; if (cl_ < K) pb[cl_ * D + bcol] = ACC[2]; } \
        { int cl_ = (M)*16 + 4*g + 3; if (cl_ < K) pb[cl_ * D + bcol] = ACC[3]; } }
        WBK(0, bacc0) WBK(1, bacc1) WBK(2, bacc2) WBK(3, bacc3)
#undef WBK
    }
    __syncthreads();
    for (int k = tid; k < K; k += BLK) atomicAdd(&out[KD + k], (float)scnt[k]);
}

// partial reduction: 8 slices of 64 partials, atomicAdd into zeroed out
__global__ __launch_bounds__(256)
void k_reduce(const float* __restrict__ partial, float* __restrict__ out, int G) {
    const int j  = blockIdx.x * 256 + threadIdx.x;    // < KD
    const int bs = G / 8;
    const int b0 = blockIdx.y * bs;
    float s = 0.f;
    for (int b = b0; b < b0 + bs; ++b) s += partial[(size_t)b * KD + j];
    atomicAdd(&out[j], s);
}

extern "C" void kernel_launch(void* const* d_in, const int* in_sizes, int n_in,
                              void* d_out, int out_size, void* d_ws, size_t ws_size,
                              hipStream_t stream) {
    const float* x = (const float*)d_in[0];
    const float* c = (const float*)d_in[1];
    float* out = (float*)d_out;
    const int N = in_sizes[0] / D;

    float* partial = (float*)d_ws;
    const size_t need = (size_t)GRID * KD * sizeof(float);
    const int useAtomic = (ws_size < need) ? 1 : 0;

    hipMemsetAsync(d_out, 0, (size_t)out_size * sizeof(float), stream);
    k_fused<<<GRID, BLK, 0, stream>>>(x, c, partial, out, N, useAtomic);
    if (!useAtomic) {
        k_reduce<<<dim3(KD / 256, 8), 256, 0, stream>>>(partial, out, GRID);
    }
}